// Round 1
// baseline (197.823 us; speedup 1.0000x reference)
//
#include <hip/hip_runtime.h>

// HyperbolicAggregation: out = proj(expmap0(A @ x, c=1), c=1)
// A is sparse (rows sorted), x is [50000, 128] f32.
// One wave (64 lanes) per node; 2 f32 accumulators per lane (d=128).

#define MIN_NORM 1e-15f
#define PROJ_EPS 4e-3f

__global__ __launch_bounds__(256) void hyp_agg_kernel(
    const float* __restrict__ x,
    const float* __restrict__ vals,
    const int* __restrict__ rows,
    const int* __restrict__ cols,
    float* __restrict__ out,
    int n_nodes, int n_edges)
{
    const int wave_id = (int)((blockIdx.x * blockDim.x + threadIdx.x) >> 6);
    const int lane = threadIdx.x & 63;
    if (wave_id >= n_nodes) return;
    const int node = wave_id;

    // rows is sorted: edge range for `node` via two lower_bounds (wave-uniform).
    int lo = 0, hi = n_edges;
    while (lo < hi) {
        int mid = (lo + hi) >> 1;
        if (rows[mid] < node) lo = mid + 1; else hi = mid;
    }
    const int start = lo;
    hi = n_edges;
    while (lo < hi) {
        int mid = (lo + hi) >> 1;
        if (rows[mid] <= node) lo = mid + 1; else hi = mid;
    }
    const int end = lo;

    float a0 = 0.f, a1 = 0.f;

    int e = start;
    // Unroll x4: 4 gathers in flight per iteration for memory-level parallelism.
    for (; e + 3 < end; e += 4) {
        float v0 = vals[e + 0], v1 = vals[e + 1], v2 = vals[e + 2], v3 = vals[e + 3];
        int   c0 = cols[e + 0], c1 = cols[e + 1], c2 = cols[e + 2], c3 = cols[e + 3];
        float2 x0 = reinterpret_cast<const float2*>(x + (size_t)c0 * 128)[lane];
        float2 x1 = reinterpret_cast<const float2*>(x + (size_t)c1 * 128)[lane];
        float2 x2 = reinterpret_cast<const float2*>(x + (size_t)c2 * 128)[lane];
        float2 x3 = reinterpret_cast<const float2*>(x + (size_t)c3 * 128)[lane];
        a0 = fmaf(v0, x0.x, a0); a1 = fmaf(v0, x0.y, a1);
        a0 = fmaf(v1, x1.x, a0); a1 = fmaf(v1, x1.y, a1);
        a0 = fmaf(v2, x2.x, a0); a1 = fmaf(v2, x2.y, a1);
        a0 = fmaf(v3, x3.x, a0); a1 = fmaf(v3, x3.y, a1);
    }
    for (; e < end; ++e) {
        float v = vals[e];
        int   c = cols[e];
        float2 xc = reinterpret_cast<const float2*>(x + (size_t)c * 128)[lane];
        a0 = fmaf(v, xc.x, a0); a1 = fmaf(v, xc.y, a1);
    }

    // Wave-wide sum of squares (64 lanes, butterfly).
    float nrm2 = fmaf(a0, a0, a1 * a1);
    #pragma unroll
    for (int off = 32; off > 0; off >>= 1) nrm2 += __shfl_xor(nrm2, off, 64);

    // expmap0 (sqrt_c = 1): y = tanh(||u||) * u / ||u||
    float u_norm = fmaxf(sqrtf(nrm2), MIN_NORM);
    float t = tanhf(u_norm);
    float scale = t / u_norm;
    float y0 = scale * a0;
    float y1 = scale * a1;

    // proj: ||y|| == tanh(||u||) == t (exact in real arithmetic).
    const float maxnorm = 1.0f - PROJ_EPS;
    if (t > maxnorm) {
        float s = maxnorm / t;
        y0 *= s;
        y1 *= s;
    }

    reinterpret_cast<float2*>(out + (size_t)node * 128)[lane] = make_float2(y0, y1);
}

extern "C" void kernel_launch(void* const* d_in, const int* in_sizes, int n_in,
                              void* d_out, int out_size, void* d_ws, size_t ws_size,
                              hipStream_t stream) {
    const float* x    = (const float*)d_in[0];
    const float* vals = (const float*)d_in[1];
    const int*   rows = (const int*)d_in[2];
    const int*   cols = (const int*)d_in[3];
    float* out = (float*)d_out;

    const int d_feat  = 128;
    const int n_nodes = in_sizes[0] / d_feat;
    const int n_edges = in_sizes[1];

    const int block = 256;                 // 4 waves per block, 1 node per wave
    const int waves_per_block = block / 64;
    const int grid = (n_nodes + waves_per_block - 1) / waves_per_block;
    hyp_agg_kernel<<<grid, block, 0, stream>>>(x, vals, rows, cols, out, n_nodes, n_edges);
}

// Round 2
// 135.195 us; speedup vs baseline: 1.4632x; 1.4632x over previous
//
#include <hip/hip_runtime.h>

// HyperbolicAggregation: out = proj(expmap0(A @ x, c=1), c=1)
// A sparse (rows sorted), x [50000,128] f32.
// Kernel 1: build row_ptr (CSR offsets) via parallel binary search -> d_ws.
// Kernel 2: one wave per node; float4 gathers, 2 edge-rows per load instr
//           (lanes 0-31 -> edge e, lanes 32-63 -> edge e+1).

#define MIN_NORM 1e-15f
#define PROJ_EPS 4e-3f

__global__ __launch_bounds__(256) void build_rowptr_kernel(
    const int* __restrict__ rows, int* __restrict__ row_ptr,
    int n_nodes, int n_edges)
{
    int i = blockIdx.x * blockDim.x + threadIdx.x;
    if (i > n_nodes) return;
    int lo = 0, hi = n_edges;
    while (lo < hi) {
        int mid = (lo + hi) >> 1;
        if (rows[mid] < i) lo = mid + 1; else hi = mid;
    }
    row_ptr[i] = lo;   // row_ptr[0]=0-ish (first >= 0), row_ptr[n_nodes]=n_edges
}

__global__ __launch_bounds__(256) void hyp_agg_kernel(
    const float* __restrict__ x,
    const float* __restrict__ vals,
    const int* __restrict__ rows,
    const int* __restrict__ cols,
    const int* __restrict__ row_ptr,   // may be null -> inline binary search
    float* __restrict__ out,
    int n_nodes, int n_edges)
{
    const int node = (int)((blockIdx.x * blockDim.x + threadIdx.x) >> 6);
    const int lane = threadIdx.x & 63;
    if (node >= n_nodes) return;
    const int half = lane >> 5;    // 0: even edges, 1: odd edges
    const int l32  = lane & 31;    // feature slot: float4 at l32*4

    int start, end;
    if (row_ptr) {
        start = row_ptr[node];
        end   = row_ptr[node + 1];
    } else {
        int lo = 0, hi = n_edges;
        while (lo < hi) { int mid = (lo + hi) >> 1; if (rows[mid] < node) lo = mid + 1; else hi = mid; }
        start = lo; hi = n_edges;
        while (lo < hi) { int mid = (lo + hi) >> 1; if (rows[mid] <= node) lo = mid + 1; else hi = mid; }
        end = lo;
    }

    float ax = 0.f, ay = 0.f, az = 0.f, aw = 0.f;

    int e = start + half;
    // Each half-wave strides by 2; unroll 4 -> 8 edges in flight per wave-iter.
    for (; e + 6 < end; e += 8) {
        float v0 = vals[e], v1 = vals[e + 2], v2 = vals[e + 4], v3 = vals[e + 6];
        int   c0 = cols[e], c1 = cols[e + 2], c2 = cols[e + 4], c3 = cols[e + 6];
        float4 x0 = reinterpret_cast<const float4*>(x + (size_t)c0 * 128)[l32];
        float4 x1 = reinterpret_cast<const float4*>(x + (size_t)c1 * 128)[l32];
        float4 x2 = reinterpret_cast<const float4*>(x + (size_t)c2 * 128)[l32];
        float4 x3 = reinterpret_cast<const float4*>(x + (size_t)c3 * 128)[l32];
        ax = fmaf(v0, x0.x, ax); ay = fmaf(v0, x0.y, ay); az = fmaf(v0, x0.z, az); aw = fmaf(v0, x0.w, aw);
        ax = fmaf(v1, x1.x, ax); ay = fmaf(v1, x1.y, ay); az = fmaf(v1, x1.z, az); aw = fmaf(v1, x1.w, aw);
        ax = fmaf(v2, x2.x, ax); ay = fmaf(v2, x2.y, ay); az = fmaf(v2, x2.z, az); aw = fmaf(v2, x2.w, aw);
        ax = fmaf(v3, x3.x, ax); ay = fmaf(v3, x3.y, ay); az = fmaf(v3, x3.z, az); aw = fmaf(v3, x3.w, aw);
    }
    for (; e < end; e += 2) {
        float v = vals[e];
        int   c = cols[e];
        float4 xc = reinterpret_cast<const float4*>(x + (size_t)c * 128)[l32];
        ax = fmaf(v, xc.x, ax); ay = fmaf(v, xc.y, ay); az = fmaf(v, xc.z, az); aw = fmaf(v, xc.w, aw);
    }

    // Combine even/odd halves: lane i and lane i+32 hold the same feature slots.
    ax += __shfl_xor(ax, 32, 64);
    ay += __shfl_xor(ay, 32, 64);
    az += __shfl_xor(az, 32, 64);
    aw += __shfl_xor(aw, 32, 64);

    // Norm^2 across 32 lanes (lanes 32-63 are mirrors; butterfly width 32).
    float nrm2 = fmaf(ax, ax, fmaf(ay, ay, fmaf(az, az, aw * aw)));
    #pragma unroll
    for (int off = 16; off > 0; off >>= 1) nrm2 += __shfl_xor(nrm2, off, 64);

    // expmap0 (sqrt_c=1): y = tanh(||u||)/||u|| * u;  proj: ||y||==tanh(||u||).
    float u_norm = fmaxf(sqrtf(nrm2), MIN_NORM);
    float t = tanhf(u_norm);
    float scale = t / u_norm;
    const float maxnorm = 1.0f - PROJ_EPS;
    if (t > maxnorm) scale *= maxnorm / t;

    if (half == 0) {
        float4 y = make_float4(scale * ax, scale * ay, scale * az, scale * aw);
        reinterpret_cast<float4*>(out + (size_t)node * 128)[l32] = y;
    }
}

extern "C" void kernel_launch(void* const* d_in, const int* in_sizes, int n_in,
                              void* d_out, int out_size, void* d_ws, size_t ws_size,
                              hipStream_t stream) {
    const float* x    = (const float*)d_in[0];
    const float* vals = (const float*)d_in[1];
    const int*   rows = (const int*)d_in[2];
    const int*   cols = (const int*)d_in[3];
    float* out = (float*)d_out;

    const int d_feat  = 128;
    const int n_nodes = in_sizes[0] / d_feat;
    const int n_edges = in_sizes[1];

    int* row_ptr = nullptr;
    const size_t need = (size_t)(n_nodes + 1) * sizeof(int);
    if (d_ws && ws_size >= need) {
        row_ptr = (int*)d_ws;
        const int b1 = 256;
        const int g1 = (n_nodes + 1 + b1 - 1) / b1;
        build_rowptr_kernel<<<g1, b1, 0, stream>>>(rows, row_ptr, n_nodes, n_edges);
    }

    const int block = 256;                 // 4 waves/block, 1 node per wave
    const int waves_per_block = block / 64;
    const int grid = (n_nodes + waves_per_block - 1) / waves_per_block;
    hyp_agg_kernel<<<grid, block, 0, stream>>>(x, vals, rows, cols, row_ptr, out,
                                               n_nodes, n_edges);
}